// Round 3
// baseline (129.660 us; speedup 1.0000x reference)
//
#include <hip/hip_runtime.h>

// FullRelPos: out[b,hw,g, kh*32+kw] = attn[...] + lh[kh] + lw[kw]
//   lh[k] = dot(q[row, 0:32],  rel_emb_h[k-h+31, :])
//   lw[k] = dot(q[row,32:64],  rel_emb_w[k-w+31, :])
//
// Two-kernel split: R1's fused kernel ran all waves through a latency-bound
// compute phase in lock-step, then a shfl-interleaved stream -> only 4.2 TB/s
// effective. Kernel 1 computes the 64 logits/row into d_ws (16 MB, coalesced).
// Kernel 2 is a pure triad stream: attn + logits -> out, no cross-lane ops.

#define QL 1024    // H*W
#define NROWS_TOTAL 65536

// ---------- kernel 1: logits[row][0:32]=lh, [32:64]=lw ----------
__global__ __launch_bounds__(256) void logits_kernel(
    const float* __restrict__ q,
    const float* __restrict__ reh,
    const float* __restrict__ rew,
    float* __restrict__ lg,
    int ntasks)
{
    const int lane = threadIdx.x & 63;
    const int wid  = blockIdx.x * 4 + (threadIdx.x >> 6);
    const int nwaves = gridDim.x * 4;

    for (int t = wid; t < ntasks; t += nwaves) {
        const int hw = t & (QL - 1);         // task = (b, hw); 8 g-rows per task
        const int h  = hw >> 5;
        const int w  = hw & 31;
        const size_t r0 = (size_t)t << 3;

        const int k = lane & 31;             // lanes 0..31 -> lh[k], 32..63 -> lw[k]
        const float4* e4 = (lane < 32)
            ? (const float4*)(reh + (size_t)(k - h + 31) * 32)
            : (const float4*)(rew + (size_t)(k - w + 31) * 32);
        const float* qbase = q + r0 * 64 + (lane & 32);

        float acc[8];
        #pragma unroll
        for (int g = 0; g < 8; ++g) acc[g] = 0.f;
        #pragma unroll
        for (int c4 = 0; c4 < 8; ++c4) {
            const float4 ev = e4[c4];
            #pragma unroll
            for (int g = 0; g < 8; ++g) {
                const float4 qv = *(const float4*)(qbase + g * 64 + c4 * 4);
                acc[g] += qv.x * ev.x + qv.y * ev.y + qv.z * ev.z + qv.w * ev.w;
            }
        }
        #pragma unroll
        for (int g = 0; g < 8; ++g)
            lg[(r0 + g) * 64 + lane] = acc[g];   // 256B coalesced per store
    }
}

// ---------- kernel 2: pure stream add ----------
__global__ __launch_bounds__(256) void stream_add_kernel(
    const float* __restrict__ attn,
    const float* __restrict__ lg,
    float* __restrict__ out,
    int nrows)
{
    const int lane = threadIdx.x & 63;
    const int wid  = blockIdx.x * 4 + (threadIdx.x >> 6);
    const int kh0 = lane >> 3;               // lane's unit u = lane+64j: kh = kh0+8j
    const int kw0 = (lane << 2) & 31;        // kw base, j-invariant

    const size_t r0 = (size_t)wid << 3;      // 8 consecutive rows per wave
    #pragma unroll
    for (int g = 0; g < 8; ++g) {
        const size_t r = r0 + g;
        const float4* arow = (const float4*)(attn + r * QL);
        const float*  lrow = lg + r * 64;

        // issue all independent loads up front
        float4 a0 = arow[lane];
        float4 a1 = arow[lane + 64];
        float4 a2 = arow[lane + 128];
        float4 a3 = arow[lane + 192];
        const float4 lw4 = *(const float4*)(lrow + 32 + kw0);
        const float lh0 = lrow[kh0];
        const float lh1 = lrow[kh0 + 8];
        const float lh2 = lrow[kh0 + 16];
        const float lh3 = lrow[kh0 + 24];

        float4* orow = (float4*)(out + r * QL);
        float4 o;
        o.x = a0.x + lh0 + lw4.x; o.y = a0.y + lh0 + lw4.y;
        o.z = a0.z + lh0 + lw4.z; o.w = a0.w + lh0 + lw4.w;
        orow[lane] = o;
        o.x = a1.x + lh1 + lw4.x; o.y = a1.y + lh1 + lw4.y;
        o.z = a1.z + lh1 + lw4.z; o.w = a1.w + lh1 + lw4.w;
        orow[lane + 64] = o;
        o.x = a2.x + lh2 + lw4.x; o.y = a2.y + lh2 + lw4.y;
        o.z = a2.z + lh2 + lw4.z; o.w = a2.w + lh2 + lw4.w;
        orow[lane + 128] = o;
        o.x = a3.x + lh3 + lw4.x; o.y = a3.y + lh3 + lw4.y;
        o.z = a3.z + lh3 + lw4.z; o.w = a3.w + lh3 + lw4.w;
        orow[lane + 192] = o;
    }
}

// ---------- fallback (R1 fused) if workspace too small ----------
__global__ __launch_bounds__(256) void relpos_fused_kernel(
    const float* __restrict__ q,
    const float* __restrict__ attn,
    const float* __restrict__ reh,
    const float* __restrict__ rew,
    float* __restrict__ out,
    int ntasks)
{
    const int lane = threadIdx.x & 63;
    const int wid  = blockIdx.x * 4 + (threadIdx.x >> 6);
    const int nwaves = gridDim.x * 4;
    for (int t = wid; t < ntasks; t += nwaves) {
        const int hw = t & (QL - 1);
        const int h  = hw >> 5;
        const int w  = hw & 31;
        const size_t r0 = (size_t)t << 3;
        const int k = lane & 31;
        const float4* e4 = (lane < 32)
            ? (const float4*)(reh + (size_t)(k - h + 31) * 32)
            : (const float4*)(rew + (size_t)(k - w + 31) * 32);
        const float* qbase = q + r0 * 64 + (lane & 32);
        float acc[8];
        #pragma unroll
        for (int g = 0; g < 8; ++g) acc[g] = 0.f;
        #pragma unroll
        for (int c4 = 0; c4 < 8; ++c4) {
            const float4 ev = e4[c4];
            #pragma unroll
            for (int g = 0; g < 8; ++g) {
                const float4 qv = *(const float4*)(qbase + g * 64 + c4 * 4);
                acc[g] += qv.x * ev.x + qv.y * ev.y + qv.z * ev.z + qv.w * ev.w;
            }
        }
        const int kw0 = (lane << 2) & 31;
        const int kh0 = lane >> 3;
        #pragma unroll
        for (int g = 0; g < 8; ++g) {
            const float a = acc[g];
            const float lw0 = __shfl(a, 32 + kw0,     64);
            const float lw1 = __shfl(a, 32 + kw0 + 1, 64);
            const float lw2 = __shfl(a, 32 + kw0 + 2, 64);
            const float lw3 = __shfl(a, 32 + kw0 + 3, 64);
            float lhv[4];
            lhv[0] = __shfl(a, kh0,      64);
            lhv[1] = __shfl(a, kh0 + 8,  64);
            lhv[2] = __shfl(a, kh0 + 16, 64);
            lhv[3] = __shfl(a, kh0 + 24, 64);
            const float4* arow = (const float4*)(attn + (r0 + g) * QL);
            float4*       orow = (float4*)(out  + (r0 + g) * QL);
            #pragma unroll
            for (int j = 0; j < 4; ++j) {
                float4 av = arow[lane + 64 * j];
                const float tl = lhv[j];
                float4 o;
                o.x = av.x + tl + lw0;
                o.y = av.y + tl + lw1;
                o.z = av.z + tl + lw2;
                o.w = av.w + tl + lw3;
                orow[lane + 64 * j] = o;
            }
        }
    }
}

extern "C" void kernel_launch(void* const* d_in, const int* in_sizes, int n_in,
                              void* d_out, int out_size, void* d_ws, size_t ws_size,
                              hipStream_t stream) {
    const float* q    = (const float*)d_in[0];
    const float* attn = (const float*)d_in[1];
    const float* reh  = (const float*)d_in[2];
    const float* rew  = (const float*)d_in[3];
    float* out = (float*)d_out;

    const int nrows  = in_sizes[1] / QL;   // B * QL * G = 65536
    const int ntasks = nrows >> 3;         // 8192

    const size_t lg_bytes = (size_t)nrows * 64 * sizeof(float);  // 16 MB
    if (ws_size >= lg_bytes) {
        float* lg = (float*)d_ws;
        logits_kernel<<<2048, 256, 0, stream>>>(q, reh, rew, lg, ntasks);
        stream_add_kernel<<<2048, 256, 0, stream>>>(attn, lg, out, nrows);
    } else {
        relpos_fused_kernel<<<2048, 256, 0, stream>>>(q, attn, reh, rew, out, ntasks);
    }
}

// Round 5
// 111.381 us; speedup vs baseline: 1.1641x; 1.1641x over previous
//
#include <hip/hip_runtime.h>

// FullRelPos: out[b,hw,g, kh*32+kw] = attn[...] + lh[kh] + lw[kw]
//   lh[k] = dot(q[row, 0:32],  rel_emb_h[k-h+31, :])
//   lw[k] = dot(q[row,32:64],  rel_emb_w[k-w+31, :])
//
// Fused, one wave per (b,hw) task (8 g-rows = 32KB stream).
// (1) all shfl redistribution hoisted before the stream,
// (2) 2-deep double-buffered attn loads across g (counted vmcnt),
// (3) nontemporal out-stores via clang ext_vector (HIP float4 is rejected
//     by __builtin_nontemporal_store).

#define QL 1024    // H*W

typedef float floatx4 __attribute__((ext_vector_type(4)));

__global__ __launch_bounds__(256) void relpos_fused2_kernel(
    const float* __restrict__ q,
    const float* __restrict__ attn,
    const float* __restrict__ reh,
    const float* __restrict__ rew,
    float* __restrict__ out,
    int ntasks)
{
    const int lane = threadIdx.x & 63;
    const int wid  = blockIdx.x * 4 + (threadIdx.x >> 6);
    const int nwaves = gridDim.x * 4;

    for (int t = wid; t < ntasks; t += nwaves) {
        const int hw = t & (QL - 1);         // task = (b, hw); 8 g-rows per task
        const int h  = hw >> 5;
        const int w  = hw & 31;
        const size_t r0 = (size_t)t << 3;

        // ---- logits: lanes 0..31 own lh[k], lanes 32..63 own lw[k] ----
        const int k = lane & 31;
        const float4* e4 = (lane < 32)
            ? (const float4*)(reh + (size_t)(k - h + 31) * 32)
            : (const float4*)(rew + (size_t)(k - w + 31) * 32);
        const float* qbase = q + r0 * 64 + (lane & 32);

        float acc[8];
        #pragma unroll
        for (int g = 0; g < 8; ++g) acc[g] = 0.f;
        #pragma unroll
        for (int c4 = 0; c4 < 8; ++c4) {
            const float4 ev = e4[c4];
            #pragma unroll
            for (int g = 0; g < 8; ++g) {
                const float4 qv = *(const float4*)(qbase + g * 64 + c4 * 4);
                acc[g] += qv.x * ev.x + qv.y * ev.y + qv.z * ev.z + qv.w * ev.w;
            }
        }

        // ---- redistribute ALL logits up front (no shfls in the stream loop) ----
        // lane's float4 unit u = lane + 64*j: kh = lane/8 + 8j, kw0 = (4*lane)&31
        const int kw0 = (lane << 2) & 31;
        const int kh0 = lane >> 3;
        float lh[8][4], lw[8][4];
        #pragma unroll
        for (int g = 0; g < 8; ++g) {
            const float a = acc[g];
            lh[g][0] = __shfl(a, kh0,      64);
            lh[g][1] = __shfl(a, kh0 + 8,  64);
            lh[g][2] = __shfl(a, kh0 + 16, 64);
            lh[g][3] = __shfl(a, kh0 + 24, 64);
            lw[g][0] = __shfl(a, 32 + kw0,     64);
            lw[g][1] = __shfl(a, 32 + kw0 + 1, 64);
            lw[g][2] = __shfl(a, 32 + kw0 + 2, 64);
            lw[g][3] = __shfl(a, 32 + kw0 + 3, 64);
        }

        // ---- stream: 2-deep double-buffered loads, nontemporal stores ----
        const float4* abase = (const float4*)(attn + r0 * QL);
        floatx4*      obase = (floatx4*)(out  + r0 * QL);

        float4 buf[2][4];
        #pragma unroll
        for (int j = 0; j < 4; ++j)
            buf[0][j] = abase[lane + 64 * j];

        #pragma unroll
        for (int g = 0; g < 8; ++g) {
            if (g < 7) {
                const float4* anext = abase + (size_t)(g + 1) * 256;
                #pragma unroll
                for (int j = 0; j < 4; ++j)
                    buf[(g + 1) & 1][j] = anext[lane + 64 * j];
            }
            floatx4* orow = obase + (size_t)g * 256;
            #pragma unroll
            for (int j = 0; j < 4; ++j) {
                const float4 a = buf[g & 1][j];
                const float tl = lh[g][j];
                floatx4 o;
                o.x = a.x + tl + lw[g][0];
                o.y = a.y + tl + lw[g][1];
                o.z = a.z + tl + lw[g][2];
                o.w = a.w + tl + lw[g][3];
                __builtin_nontemporal_store(o, &orow[lane + 64 * j]);
            }
        }
    }
}

extern "C" void kernel_launch(void* const* d_in, const int* in_sizes, int n_in,
                              void* d_out, int out_size, void* d_ws, size_t ws_size,
                              hipStream_t stream) {
    const float* q    = (const float*)d_in[0];
    const float* attn = (const float*)d_in[1];
    const float* reh  = (const float*)d_in[2];
    const float* rew  = (const float*)d_in[3];
    float* out = (float*)d_out;

    const int nrows  = in_sizes[1] / QL;   // B * QL * G = 65536
    const int ntasks = nrows >> 3;         // 8192 -> one per wave
    relpos_fused2_kernel<<<2048, 256, 0, stream>>>(q, attn, reh, rew, out, ntasks);
}